// Round 19
// baseline (5494.979 us; speedup 1.0000x reference)
//
#include <hip/hip_runtime.h>

// LSTM forward, B=32 T=1024 D=512 U=512, fp32.
// Persistent fused kernel, 256 WGs x 512 thr (all co-resident, grid == #CUs).
// Group g = blockIdx&7 (batches 4g..4g+3); WG w = blockIdx>>3 owns units
// [16w,16w+16). Weights in VGPRs as f32x2 col-pairs. Base = R16 (best).
//
// R19 = R18 with the tag-period bug fixed (R18 failed: period-4 tagging vs
// provable skew bound -> stale t-5 reads ACCEPTED; absmax 4.8e-2).
// Clean same-XCD L2 exchange -- detect==data, no tags, no producer wait:
//  - |h| < 1 strictly => enc = h + (color? +3 : -3) lies in +/-[2,4):
//    biased exp == 128 (129 at the 4.0 edge), sign = color.
//  - slot = t & 3 (4 slots), color = (t>>2)&1 -> combined period 8.
//    Skew lemma: WG stores h(t) => all WGs stored h(t-1) (B2 couples the 4
//    waves whose polls cover all 32 producers). So a consumer polling t-1
//    can at worst meet a producer whose last same-slot write is t-5; with
//    period 8, t-5 has FLIPPED color -> rejected. t-9 overwritten. Sound.
//  - Producer: sc0-store enc to ring (no waitcnt) + sc1-store exact h to out
//    (output + fallback sentinel). Tail cost == R16 + one store issue.
//  - Consumer: poll its 8 ring words (sc0, one L2 RTT); valid iff exp in
//    {128,129} and sign == color. Decode h = enc -/+ 3 (err <= 2^-22).
//  - Hybrid: every 8th miss, one R16 SENTSHOT on out => live under any mix.
//  - Fast mode iff runtime XCD check passes (R17-proven); else exact R16.

#define TT 1024
#define DD 512
#define UU 512
#define NCOL 2048
#define SENT 0xFFFFFFFFu
#define RDEPTH 4
// ws layout (bytes): [0,32) cnt[8]; [32,64) mask[8]; [1024, 1024+262144) ring.
#define WS_NEED 263168

typedef float f32x2 __attribute__((ext_vector_type(2)));
typedef float f32x4 __attribute__((ext_vector_type(4)));

__device__ __forceinline__ float hsig(float v) {
  return fminf(fmaxf(0.2f * v + 0.5f, 0.0f), 1.0f);
}
__device__ __forceinline__ float tanh_fast(float x) {
  float e = __expf(2.0f * x);
  return 1.0f - 2.0f / (e + 1.0f);
}

template <bool SLEEP>
__device__ __forceinline__ void wavebar(int* ctr, int& ep) {
  asm volatile("s_waitcnt lgkmcnt(0)" ::: "memory");
  if ((threadIdx.x & 63) == 0)
    __hip_atomic_fetch_add(ctr, 1, __ATOMIC_RELAXED, __HIP_MEMORY_SCOPE_WORKGROUP);
  ep += 4;
  while (__hip_atomic_load(ctr, __ATOMIC_RELAXED, __HIP_MEMORY_SCOPE_WORKGROUP) < ep) {
    if (SLEEP) __builtin_amdgcn_s_sleep(1);
  }
  asm volatile("" ::: "memory");
}

// R16-proven LLC sentinel shot (8 words, sc0 sc1, one vmcnt).
#define SENTSHOT(v0,v1,v2,v3,v4,v5,v6,v7,p0,p1,p2,p3)                    \
  asm volatile(                                                          \
      "global_load_dword %0, %8, off sc0 sc1\n\t"                        \
      "global_load_dword %1, %8, off offset:256 sc0 sc1\n\t"             \
      "global_load_dword %2, %9, off sc0 sc1\n\t"                        \
      "global_load_dword %3, %9, off offset:256 sc0 sc1\n\t"             \
      "global_load_dword %4, %10, off sc0 sc1\n\t"                       \
      "global_load_dword %5, %10, off offset:256 sc0 sc1\n\t"            \
      "global_load_dword %6, %11, off sc0 sc1\n\t"                       \
      "global_load_dword %7, %11, off offset:256 sc0 sc1\n\t"            \
      "s_waitcnt vmcnt(0)"                                               \
      : "=v"(v0), "=v"(v1), "=v"(v2), "=v"(v3),                          \
        "=v"(v4), "=v"(v5), "=v"(v6), "=v"(v7)                           \
      : "v"(p0), "v"(p1), "v"(p2), "v"(p3)                               \
      : "memory")

#define OK8(v0,v1,v2,v3,v4,v5,v6,v7)                                     \
  ((v0 != SENT) & (v1 != SENT) & (v2 != SENT) & (v3 != SENT) &           \
   (v4 != SENT) & (v5 != SENT) & (v6 != SENT) & (v7 != SENT))

// Encoded-word validity: exp in {128,129} and sign == expsign.
__device__ __forceinline__ int encok(unsigned b, unsigned expsign) {
  unsigned e = (b >> 23) & 0xFF;
  return (int)(((e == 128u) | (e == 129u)) & ((b >> 31) == expsign));
}

__global__ __launch_bounds__(512, 2) void lstm_persistent(
    const float* __restrict__ x,
    const float* __restrict__ Wk,
    const float* __restrict__ Wr,
    const float* __restrict__ bias,
    float* __restrict__ out,
    int* __restrict__ wsbase) {   // nullptr => pure R16 slow path
  const int tid = (int)threadIdx.x;
  const int g   = (int)blockIdx.x & 7;
  const int w   = (int)blockIdx.x >> 3;
  const bool crit = (tid < 256);
  const int l   = tid & 63;
  const bool has_ws = (wsbase != nullptr);

  int* wscnt  = wsbase;                  // [g]
  int* wsmask = wsbase + 8;              // [g]
  float* ring = (float*)wsbase + 256;    // [((g*4+slot)*4+b)*512+u]

  // Publish arrival + XCD id early (overlaps the weight loads below).
  if (has_ws && tid == 0) {
    unsigned xcd;
    asm volatile("s_getreg_b32 %0, hwreg(HW_REG_XCC_ID)" : "=s"(xcd));
    __hip_atomic_fetch_or(wsmask + g, 1u << (xcd & 31), __ATOMIC_RELAXED,
                          __HIP_MEMORY_SCOPE_AGENT);
    __hip_atomic_fetch_add(wscnt + g, 1, __ATOMIC_RELEASE,
                           __HIP_MEMORY_SCOPE_AGENT);
  }

  __shared__ float LX[8][4][65];
  __shared__ float LR[2][8][4][66];
  __shared__ float RING[RDEPTH][4][66];
  __shared__ float LH[4][8][68];
  __shared__ float LB[64];
  __shared__ int cXZdone, cCRITdone, cXZbar, cCRITbar, sFast;

  if (tid == 0) { cXZdone = 0; cCRITdone = 0; cXZbar = 0; cCRITbar = 0; }
  if (tid < 64) LB[tid] = bias[(tid >> 4) * UU + w * 16 + (tid & 15)];

  f32x2 W2[64];
  {
    const int wv  = tid >> 6;
    const int idx = tid & 255;
    const int cp  = crit ? (l & 31) : (idx & 31);
    const int ko  = crit ? (2 * (wv & 3) + (l >> 5)) : (idx >> 5);
    const int gcb = (cp >> 3) * UU + w * 16 + ((2 * cp) & 15);
    const float* M = crit ? Wr : Wk;
#pragma unroll
    for (int j = 0; j < 64; ++j)
      W2[j] = *(const f32x2*)(M + (size_t)(64 * ko + j) * NCOL + gcb);
  }
  // Resolve mode: fast iff all 32 group WGs on one XCD (bounded spin).
  if (tid == 0) {
    int fast = 0;
    if (has_ws) {
      int ok = 0;
      for (int it = 0; it < 200000; ++it) {
        if (__hip_atomic_load(wscnt + g, __ATOMIC_ACQUIRE,
                              __HIP_MEMORY_SCOPE_AGENT) >= 32) { ok = 1; break; }
        __builtin_amdgcn_s_sleep(8);
      }
      if (ok) {
        unsigned m = (unsigned)__hip_atomic_load(wsmask + g, __ATOMIC_RELAXED,
                                                 __HIP_MEMORY_SCOPE_AGENT);
        fast = (__popc(m) == 1) ? 1 : 0;
      }
    }
    sFast = fast;
  }
  __syncthreads();  // one-time init barrier
  const bool fastm = (sFast != 0);

  if (crit) {
    // ---------------- critical path: waves 0-3 ----------------
    const int wv  = tid >> 6;        // wave id; poll-slice + batch wv
    const int kq0 = 2 * wv;
    const int kql = kq0 + (l >> 5);
    const int cp  = l & 31;
    const unsigned* ou0 = (const unsigned*)out + (size_t)(g * 4 + 0) * TT * UU;
    const unsigned* ou1 = (const unsigned*)out + (size_t)(g * 4 + 1) * TT * UU;
    const unsigned* ou2 = (const unsigned*)out + (size_t)(g * 4 + 2) * TT * UU;
    const unsigned* ou3 = (const unsigned*)out + (size_t)(g * 4 + 3) * TT * UU;
    float c_state = 0.0f;            // lanes 0-15: c for (batch wv, unit l)
    int epC = 0;

    for (int t = 0; t < TT; ++t) {
      if (t > 0) {
        const size_t roff = (size_t)(t - 1) * UU + 128 * wv + l;
        const unsigned* p0 = ou0 + roff;
        const unsigned* p1 = ou1 + roff;
        const unsigned* p2 = ou2 + roff;
        const unsigned* p3 = ou3 + roff;
        unsigned v0, v1, v2, v3, v4, v5, v6, v7;
        float h0v, h1v, h2v, h3v, h4v, h5v, h6v, h7v;
        if (fastm) {
          // ---- L2 detect==data poll on encoded ring (period-8 tag) ----
          const int tau   = t - 1;
          const int slot  = tau & 3;
          const unsigned color = (unsigned)((tau >> 2) & 1);
          const unsigned expsign = color ? 0u : 1u;  // +3 bias -> sign 0
          const float dec = color ? -3.0f : 3.0f;    // h = enc + dec
          const unsigned* fb0 = (const unsigned*)ring +
              ((size_t)((g * 4 + slot) * 4 + 0)) * 512 + 128 * wv + l;
          const unsigned* fb1 = (const unsigned*)ring +
              ((size_t)((g * 4 + slot) * 4 + 1)) * 512 + 128 * wv + l;
          const unsigned* fb2 = (const unsigned*)ring +
              ((size_t)((g * 4 + slot) * 4 + 2)) * 512 + 128 * wv + l;
          const unsigned* fb3 = (const unsigned*)ring +
              ((size_t)((g * 4 + slot) * 4 + 3)) * 512 + 128 * wv + l;
          int miss = 0;
          for (;;) {
            asm volatile(
                "global_load_dword %0, %8, off sc0\n\t"
                "global_load_dword %1, %8, off offset:256 sc0\n\t"
                "global_load_dword %2, %9, off sc0\n\t"
                "global_load_dword %3, %9, off offset:256 sc0\n\t"
                "global_load_dword %4, %10, off sc0\n\t"
                "global_load_dword %5, %10, off offset:256 sc0\n\t"
                "global_load_dword %6, %11, off sc0\n\t"
                "global_load_dword %7, %11, off offset:256 sc0\n\t"
                "s_waitcnt vmcnt(0)"
                : "=v"(v0), "=v"(v1), "=v"(v2), "=v"(v3),
                  "=v"(v4), "=v"(v5), "=v"(v6), "=v"(v7)
                : "v"(fb0), "v"(fb1), "v"(fb2), "v"(fb3)
                : "memory");
            int ok = encok(v0, expsign) & encok(v1, expsign) &
                     encok(v2, expsign) & encok(v3, expsign) &
                     encok(v4, expsign) & encok(v5, expsign) &
                     encok(v6, expsign) & encok(v7, expsign);
            if (__all(ok)) {
              h0v = __uint_as_float(v0) + dec;
              h1v = __uint_as_float(v1) + dec;
              h2v = __uint_as_float(v2) + dec;
              h3v = __uint_as_float(v3) + dec;
              h4v = __uint_as_float(v4) + dec;
              h5v = __uint_as_float(v5) + dec;
              h6v = __uint_as_float(v6) + dec;
              h7v = __uint_as_float(v7) + dec;
              break;
            }
            if (((++miss) & 7) == 0) {
              SENTSHOT(v0, v1, v2, v3, v4, v5, v6, v7, p0, p1, p2, p3);
              if (__all(OK8(v0, v1, v2, v3, v4, v5, v6, v7))) {
                h0v = __uint_as_float(v0);
                h1v = __uint_as_float(v1);
                h2v = __uint_as_float(v2);
                h3v = __uint_as_float(v3);
                h4v = __uint_as_float(v4);
                h5v = __uint_as_float(v5);
                h6v = __uint_as_float(v6);
                h7v = __uint_as_float(v7);
                break;
              }
            }
            __builtin_amdgcn_s_sleep(1);
          }
        } else {
          // ---- pure R16 slow poll ----
          for (;;) {
            SENTSHOT(v0, v1, v2, v3, v4, v5, v6, v7, p0, p1, p2, p3);
            if (__all(OK8(v0, v1, v2, v3, v4, v5, v6, v7))) break;
            __builtin_amdgcn_s_sleep(16);
          }
          h0v = __uint_as_float(v0);
          h1v = __uint_as_float(v1);
          h2v = __uint_as_float(v2);
          h3v = __uint_as_float(v3);
          h4v = __uint_as_float(v4);
          h5v = __uint_as_float(v5);
          h6v = __uint_as_float(v6);
          h7v = __uint_as_float(v7);
        }
        // ---- stage into this wave's private LH octants ----
        LH[0][kq0    ][l] = h0v;
        LH[0][kq0 + 1][l] = h1v;
        LH[1][kq0    ][l] = h2v;
        LH[1][kq0 + 1][l] = h3v;
        LH[2][kq0    ][l] = h4v;
        LH[2][kq0 + 1][l] = h5v;
        LH[3][kq0    ][l] = h6v;
        LH[3][kq0 + 1][l] = h7v;
        asm volatile("s_waitcnt lgkmcnt(0)" ::: "memory");
        __builtin_amdgcn_sched_barrier(0);
        // ---- dot: 2 cols x 64 k x 4 batches, f32x2 acc (v_pk_fma) ----
        __builtin_amdgcn_s_setprio(1);
        f32x2 a0 = {0.f, 0.f}, a1 = {0.f, 0.f}, a2 = {0.f, 0.f}, a3 = {0.f, 0.f};
#pragma unroll
        for (int j4 = 0; j4 < 16; ++j4) {
          f32x4 h0 = *(const f32x4*)&LH[0][kql][4 * j4];
          f32x4 h1 = *(const f32x4*)&LH[1][kql][4 * j4];
          f32x4 h2 = *(const f32x4*)&LH[2][kql][4 * j4];
          f32x4 h3 = *(const f32x4*)&LH[3][kql][4 * j4];
#pragma unroll
          for (int jj = 0; jj < 4; ++jj) {
            f32x2 wj = W2[4 * j4 + jj];
            a0 += (f32x2){h0[jj], h0[jj]} * wj;
            a1 += (f32x2){h1[jj], h1[jj]} * wj;
            a2 += (f32x2){h2[jj], h2[jj]} * wj;
            a3 += (f32x2){h3[jj], h3[jj]} * wj;
          }
        }
        __builtin_amdgcn_s_setprio(0);
        const int p = t & 1;
        *(f32x2*)&LR[p][kql][0][2 * cp] = a0;
        *(f32x2*)&LR[p][kql][1][2 * cp] = a1;
        *(f32x2*)&LR[p][kql][2][2 * cp] = a2;
        *(f32x2*)&LR[p][kql][3][2 * cp] = a3;
      }
      // ---- pre-gate: xz + bias for batch wv (lanes 0-15), before B2 ----
      float s0 = 0.f, s1 = 0.f, s2 = 0.f, s3 = 0.f;
      if (l < 16) {
        while (__hip_atomic_load(&cXZdone, __ATOMIC_RELAXED,
                                 __HIP_MEMORY_SCOPE_WORKGROUP) < t + 1) {
        }
        asm volatile("" ::: "memory");
        const int ss = t & (RDEPTH - 1);
        s0 = RING[ss][wv][l +  0] + LB[l +  0];
        s1 = RING[ss][wv][l + 16] + LB[l + 16];
        s2 = RING[ss][wv][l + 32] + LB[l + 32];
        s3 = RING[ss][wv][l + 48] + LB[l + 48];
      }
      wavebar<false>(&cCRITbar, epC);  // B2: all LR partials complete
      if (l == 0)
        __hip_atomic_fetch_add(&cCRITdone, 1, __ATOMIC_RELAXED,
                               __HIP_MEMORY_SCOPE_WORKGROUP);
      // ---- gates for batch wv, units w*16 + l (lanes 0-15) ----
      if (l < 16) {
        if (t > 0) {
          const int p = t & 1;
#pragma unroll
          for (int kq = 0; kq < 8; ++kq) {
            s0 += LR[p][kq][wv][l +  0];
            s1 += LR[p][kq][wv][l + 16];
            s2 += LR[p][kq][wv][l + 32];
            s3 += LR[p][kq][wv][l + 48];
          }
        }
        float gi = hsig(s0);
        float gf = hsig(s1);
        float gc = tanh_fast(s2);
        float go = hsig(s3);
        c_state = gf * c_state + gi * gc;
        float h = go * tanh_fast(c_state);
        if (fastm) {
          // encoded ring store (sc0, no wait): slot=t&3, color=(t>>2)&1
          const float enc = ((t >> 2) & 1) ? (h + 3.0f) : (h - 3.0f);
          float* fp = ring +
              ((size_t)((g * 4 + (t & 3)) * 4 + wv)) * 512 + 16 * w + l;
          asm volatile("global_store_dword %0, %1, off sc0"
                       :: "v"(fp), "v"(enc) : "memory");
        }
        // Always: output + sentinel data at LLC (liveness under any mode mix).
        __hip_atomic_store(
            out + ((size_t)(g * 4 + wv) * TT + t) * UU + w * 16 + l, h,
            __ATOMIC_RELAXED, __HIP_MEMORY_SCOPE_AGENT);
      }
    }
  } else {
    // ---------------- xz pipeline: waves 4-7 (free-running) ----------------
    const int idx = tid & 255;
    const int o   = idx >> 5;
    const int cp  = idx & 31;
    const float* xb0 = x + (size_t)(g * 4 + 0) * TT * DD + o * 64;
    const float* xb1 = x + (size_t)(g * 4 + 1) * TT * DD + o * 64;
    const float* xb2 = x + (size_t)(g * 4 + 2) * TT * DD + o * 64;
    const float* xb3 = x + (size_t)(g * 4 + 3) * TT * DD + o * 64;
    int epX = 0;

    for (int t = 0; t < TT; ++t) {
      const size_t off = (size_t)t * DD;
      f32x2 a0 = {0.f, 0.f}, a1 = {0.f, 0.f}, a2 = {0.f, 0.f}, a3 = {0.f, 0.f};
#pragma unroll
      for (int j4 = 0; j4 < 16; ++j4) {
        f32x4 v0 = *(const f32x4*)(xb0 + off + 4 * j4);
        f32x4 v1 = *(const f32x4*)(xb1 + off + 4 * j4);
        f32x4 v2 = *(const f32x4*)(xb2 + off + 4 * j4);
        f32x4 v3 = *(const f32x4*)(xb3 + off + 4 * j4);
#pragma unroll
        for (int jj = 0; jj < 4; ++jj) {
          f32x2 wj = W2[4 * j4 + jj];
          a0 += (f32x2){v0[jj], v0[jj]} * wj;
          a1 += (f32x2){v1[jj], v1[jj]} * wj;
          a2 += (f32x2){v2[jj], v2[jj]} * wj;
          a3 += (f32x2){v3[jj], v3[jj]} * wj;
        }
      }
      *(f32x2*)&LX[o][0][2 * cp] = a0;
      *(f32x2*)&LX[o][1][2 * cp] = a1;
      *(f32x2*)&LX[o][2][2 * cp] = a2;
      *(f32x2*)&LX[o][3][2 * cp] = a3;
      wavebar<true>(&cXZbar, epX);  // partials visible
      if (t >= RDEPTH) {
        while (__hip_atomic_load(&cCRITdone, __ATOMIC_RELAXED,
                                 __HIP_MEMORY_SCOPE_WORKGROUP) <
               4 * (t - RDEPTH + 1)) {
          __builtin_amdgcn_s_sleep(1);
        }
        asm volatile("" ::: "memory");
      }
      {
        const int b2 = idx >> 6, c3 = idx & 63;
        float ssum = 0.f;
#pragma unroll
        for (int oo = 0; oo < 8; ++oo) ssum += LX[oo][b2][c3];
        RING[t & (RDEPTH - 1)][b2][c3] = ssum;
      }
      wavebar<true>(&cXZbar, epX);  // reduce complete (guards LX overwrite)
      if (idx == 0) {
        asm volatile("s_waitcnt lgkmcnt(0)" ::: "memory");
        __hip_atomic_fetch_add(&cXZdone, 1, __ATOMIC_RELAXED,
                               __HIP_MEMORY_SCOPE_WORKGROUP);
      }
    }
  }
}

extern "C" void kernel_launch(void* const* d_in, const int* in_sizes, int n_in,
                              void* d_out, int out_size, void* d_ws, size_t ws_size,
                              hipStream_t stream) {
  const float* x    = (const float*)d_in[0];
  const float* Wk   = (const float*)d_in[1];
  const float* Wr   = (const float*)d_in[2];
  const float* bias = (const float*)d_in[3];
  float* out = (float*)d_out;

  int* wsbase = nullptr;
  if (ws_size >= (size_t)WS_NEED) {
    wsbase = (int*)d_ws;
    hipMemsetAsync(wsbase, 0x00, 64, stream);                    // cnt/mask = 0
    hipMemsetAsync((char*)d_ws + 1024, 0xFF, 262144, stream);    // ring = -NaN
  }
  // Sentinel-fill the h history (slow-path detect + hybrid fallback + output).
  hipMemsetAsync(out, 0xFF, (size_t)out_size * sizeof(float), stream);
  lstm_persistent<<<256, 512, 0, stream>>>(x, Wk, Wr, bias, out, wsbase);
}

// Round 20
// 4235.814 us; speedup vs baseline: 1.2973x; 1.2973x over previous
//
#include <hip/hip_runtime.h>

// LSTM forward, B=32 T=1024 D=512 U=512, fp32.  FINAL (= R16, best: 4258us).
// Persistent fused kernel, 256 WGs x 512 thr (all co-resident, grid == #CUs).
// Group g = blockIdx&7 (batches 4g..4g+3); WG w = blockIdx>>3 owns units
// [16w,16w+16). Weights in VGPRs as f32x2 col-pairs.
//
// Structure (proven over R1-R19):
//  - waves 0-3 (crit): slice-local sentinel data-poll of h(t-1) at LLC scope
//    (8 words sc0 sc1, one vmcnt; detect==data, 1 RTT) -> wave-private LDS
//    stage -> f32x2 packed dot (v_pk_fma) -> LR parity buffer -> B2 wavebar
//    -> 16-lane serial gates for batch wv -> h store (RELAXED+AGENT).
//  - waves 4-7 (xz): free-running x@K pipeline, RDEPTH=4 LDS ring, LDS
//    epoch barriers; fully off the critical path.
//  - d_out doubles as h history; memset 0xFFFFFFFF = unreachable sentinel
//    (|h|<1 always), so polled words ARE the data: no flags, no fences.
//
// Measured floor: 1024 sequential device-scope exchanges x ~4.15us
// (store->LLC-visible->detect ~3.3us + serial compute ~0.85us). All tested
// alternatives (XCD-L2 exchange, spec-load pipelining, group interleave,
// poll form/width/rate, shfl tails) were neutral or worse (R10-R19).

#define TT 1024
#define DD 512
#define UU 512
#define NCOL 2048
#define SENT 0xFFFFFFFFu
#define RDEPTH 4

typedef float f32x2 __attribute__((ext_vector_type(2)));
typedef float f32x4 __attribute__((ext_vector_type(4)));

__device__ __forceinline__ float hsig(float v) {
  return fminf(fmaxf(0.2f * v + 0.5f, 0.0f), 1.0f);
}
__device__ __forceinline__ float tanh_fast(float x) {
  float e = __expf(2.0f * x);
  return 1.0f - 2.0f / (e + 1.0f);
}

// Epoch barrier for the 4 waves of one half (waves 0-3 or 4-7).
template <bool SLEEP>
__device__ __forceinline__ void wavebar(int* ctr, int& ep) {
  asm volatile("s_waitcnt lgkmcnt(0)" ::: "memory");
  if ((threadIdx.x & 63) == 0)
    __hip_atomic_fetch_add(ctr, 1, __ATOMIC_RELAXED, __HIP_MEMORY_SCOPE_WORKGROUP);
  ep += 4;
  while (__hip_atomic_load(ctr, __ATOMIC_RELAXED, __HIP_MEMORY_SCOPE_WORKGROUP) < ep) {
    if (SLEEP) __builtin_amdgcn_s_sleep(1);
  }
  asm volatile("" ::: "memory");
}

__global__ __launch_bounds__(512, 2) void lstm_persistent(
    const float* __restrict__ x,
    const float* __restrict__ Wk,
    const float* __restrict__ Wr,
    const float* __restrict__ bias,
    float* __restrict__ out) {
  const int tid = (int)threadIdx.x;
  const int g   = (int)blockIdx.x & 7;
  const int w   = (int)blockIdx.x >> 3;
  const bool crit = (tid < 256);
  const int l   = tid & 63;

  __shared__ float LX[8][4][65];
  __shared__ float LR[2][8][4][66];
  __shared__ float RING[RDEPTH][4][66];
  __shared__ float LH[4][8][68];
  __shared__ float LB[64];
  __shared__ int cXZdone, cCRITdone, cXZbar, cCRITbar;

  if (tid == 0) { cXZdone = 0; cCRITdone = 0; cXZbar = 0; cCRITbar = 0; }
  if (tid < 64) LB[tid] = bias[(tid >> 4) * UU + w * 16 + (tid & 15)];

  f32x2 W2[64];
  {
    const int wv  = tid >> 6;
    const int idx = tid & 255;
    const int cp  = crit ? (l & 31) : (idx & 31);
    const int ko  = crit ? (2 * (wv & 3) + (l >> 5)) : (idx >> 5);
    const int gcb = (cp >> 3) * UU + w * 16 + ((2 * cp) & 15);
    const float* M = crit ? Wr : Wk;
#pragma unroll
    for (int j = 0; j < 64; ++j)
      W2[j] = *(const f32x2*)(M + (size_t)(64 * ko + j) * NCOL + gcb);
  }
  __syncthreads();  // one-time init barrier only

  if (crit) {
    // ---------------- critical path: waves 0-3 ----------------
    const int wv  = tid >> 6;        // wave id; poll-slice + batch wv
    const int kq0 = 2 * wv;
    const int kql = kq0 + (l >> 5);
    const int cp  = l & 31;
    const unsigned* ou0 = (const unsigned*)out + (size_t)(g * 4 + 0) * TT * UU;
    const unsigned* ou1 = (const unsigned*)out + (size_t)(g * 4 + 1) * TT * UU;
    const unsigned* ou2 = (const unsigned*)out + (size_t)(g * 4 + 2) * TT * UU;
    const unsigned* ou3 = (const unsigned*)out + (size_t)(g * 4 + 3) * TT * UU;
    float c_state = 0.0f;            // lanes 0-15: c for (batch wv, unit l)
    int epC = 0;

    for (int t = 0; t < TT; ++t) {
      if (t > 0) {
        // ---- slice-local data-poll: 8 words, 1 RTT, 8 producer WGs ----
        // asm sc0 sc1: bypass L1, read the LLC coherence point every iter.
        // Backoff s_sleep(16): throttle poll pressure on the LLC.
        const size_t roff = (size_t)(t - 1) * UU + 128 * wv + l;
        const unsigned* p0 = ou0 + roff;
        const unsigned* p1 = ou1 + roff;
        const unsigned* p2 = ou2 + roff;
        const unsigned* p3 = ou3 + roff;
        unsigned v0, v1, v2, v3, v4, v5, v6, v7;
        for (;;) {
          asm volatile(
              "global_load_dword %0, %8, off sc0 sc1\n\t"
              "global_load_dword %1, %8, off offset:256 sc0 sc1\n\t"
              "global_load_dword %2, %9, off sc0 sc1\n\t"
              "global_load_dword %3, %9, off offset:256 sc0 sc1\n\t"
              "global_load_dword %4, %10, off sc0 sc1\n\t"
              "global_load_dword %5, %10, off offset:256 sc0 sc1\n\t"
              "global_load_dword %6, %11, off sc0 sc1\n\t"
              "global_load_dword %7, %11, off offset:256 sc0 sc1\n\t"
              "s_waitcnt vmcnt(0)"
              : "=v"(v0), "=v"(v1), "=v"(v2), "=v"(v3),
                "=v"(v4), "=v"(v5), "=v"(v6), "=v"(v7)
              : "v"(p0), "v"(p1), "v"(p2), "v"(p3)
              : "memory");
          int ok = (v0 != SENT) & (v1 != SENT) & (v2 != SENT) & (v3 != SENT) &
                   (v4 != SENT) & (v5 != SENT) & (v6 != SENT) & (v7 != SENT);
          if (__all(ok)) break;
          __builtin_amdgcn_s_sleep(16);
        }
        // ---- stage into this wave's private LH octants ----
        LH[0][kq0    ][l] = __uint_as_float(v0);
        LH[0][kq0 + 1][l] = __uint_as_float(v1);
        LH[1][kq0    ][l] = __uint_as_float(v2);
        LH[1][kq0 + 1][l] = __uint_as_float(v3);
        LH[2][kq0    ][l] = __uint_as_float(v4);
        LH[2][kq0 + 1][l] = __uint_as_float(v5);
        LH[3][kq0    ][l] = __uint_as_float(v6);
        LH[3][kq0 + 1][l] = __uint_as_float(v7);
        asm volatile("s_waitcnt lgkmcnt(0)" ::: "memory");
        __builtin_amdgcn_sched_barrier(0);
        // ---- dot: 2 cols x 64 k x 4 batches, f32x2 acc (v_pk_fma) ----
        __builtin_amdgcn_s_setprio(1);
        f32x2 a0 = {0.f, 0.f}, a1 = {0.f, 0.f}, a2 = {0.f, 0.f}, a3 = {0.f, 0.f};
#pragma unroll
        for (int j4 = 0; j4 < 16; ++j4) {
          f32x4 h0 = *(const f32x4*)&LH[0][kql][4 * j4];
          f32x4 h1 = *(const f32x4*)&LH[1][kql][4 * j4];
          f32x4 h2 = *(const f32x4*)&LH[2][kql][4 * j4];
          f32x4 h3 = *(const f32x4*)&LH[3][kql][4 * j4];
#pragma unroll
          for (int jj = 0; jj < 4; ++jj) {
            f32x2 wj = W2[4 * j4 + jj];
            a0 += (f32x2){h0[jj], h0[jj]} * wj;
            a1 += (f32x2){h1[jj], h1[jj]} * wj;
            a2 += (f32x2){h2[jj], h2[jj]} * wj;
            a3 += (f32x2){h3[jj], h3[jj]} * wj;
          }
        }
        __builtin_amdgcn_s_setprio(0);
        const int p = t & 1;
        *(f32x2*)&LR[p][kql][0][2 * cp] = a0;
        *(f32x2*)&LR[p][kql][1][2 * cp] = a1;
        *(f32x2*)&LR[p][kql][2][2 * cp] = a2;
        *(f32x2*)&LR[p][kql][3][2 * cp] = a3;
      }
      // ---- pre-gate: xz + bias for batch wv (lanes 0-15), before B2 ----
      float s0 = 0.f, s1 = 0.f, s2 = 0.f, s3 = 0.f;
      if (l < 16) {
        while (__hip_atomic_load(&cXZdone, __ATOMIC_RELAXED,
                                 __HIP_MEMORY_SCOPE_WORKGROUP) < t + 1) {
        }
        asm volatile("" ::: "memory");
        const int ss = t & (RDEPTH - 1);
        s0 = RING[ss][wv][l +  0] + LB[l +  0];
        s1 = RING[ss][wv][l + 16] + LB[l + 16];
        s2 = RING[ss][wv][l + 32] + LB[l + 32];
        s3 = RING[ss][wv][l + 48] + LB[l + 48];
      }
      wavebar<false>(&cCRITbar, epC);  // B2: all LR partials complete
      if (l == 0)
        __hip_atomic_fetch_add(&cCRITdone, 1, __ATOMIC_RELAXED,
                               __HIP_MEMORY_SCOPE_WORKGROUP);
      // ---- gates for batch wv, units w*16 + l (lanes 0-15) ----
      if (l < 16) {
        if (t > 0) {
          const int p = t & 1;
#pragma unroll
          for (int kq = 0; kq < 8; ++kq) {
            s0 += LR[p][kq][wv][l +  0];
            s1 += LR[p][kq][wv][l + 16];
            s2 += LR[p][kq][wv][l + 32];
            s3 += LR[p][kq][wv][l + 48];
          }
        }
        float gi = hsig(s0);
        float gf = hsig(s1);
        float gc = tanh_fast(s2);
        float go = hsig(s3);
        c_state = gf * c_state + gi * gc;
        float h = go * tanh_fast(c_state);
        __hip_atomic_store(
            out + ((size_t)(g * 4 + wv) * TT + t) * UU + w * 16 + l, h,
            __ATOMIC_RELAXED, __HIP_MEMORY_SCOPE_AGENT);
      }
    }
  } else {
    // ---------------- xz pipeline: waves 4-7 (free-running) ----------------
    const int idx = tid & 255;
    const int o   = idx >> 5;
    const int cp  = idx & 31;
    const float* xb0 = x + (size_t)(g * 4 + 0) * TT * DD + o * 64;
    const float* xb1 = x + (size_t)(g * 4 + 1) * TT * DD + o * 64;
    const float* xb2 = x + (size_t)(g * 4 + 2) * TT * DD + o * 64;
    const float* xb3 = x + (size_t)(g * 4 + 3) * TT * DD + o * 64;
    int epX = 0;

    for (int t = 0; t < TT; ++t) {
      const size_t off = (size_t)t * DD;
      f32x2 a0 = {0.f, 0.f}, a1 = {0.f, 0.f}, a2 = {0.f, 0.f}, a3 = {0.f, 0.f};
#pragma unroll
      for (int j4 = 0; j4 < 16; ++j4) {
        f32x4 v0 = *(const f32x4*)(xb0 + off + 4 * j4);
        f32x4 v1 = *(const f32x4*)(xb1 + off + 4 * j4);
        f32x4 v2 = *(const f32x4*)(xb2 + off + 4 * j4);
        f32x4 v3 = *(const f32x4*)(xb3 + off + 4 * j4);
#pragma unroll
        for (int jj = 0; jj < 4; ++jj) {
          f32x2 wj = W2[4 * j4 + jj];
          a0 += (f32x2){v0[jj], v0[jj]} * wj;
          a1 += (f32x2){v1[jj], v1[jj]} * wj;
          a2 += (f32x2){v2[jj], v2[jj]} * wj;
          a3 += (f32x2){v3[jj], v3[jj]} * wj;
        }
      }
      *(f32x2*)&LX[o][0][2 * cp] = a0;
      *(f32x2*)&LX[o][1][2 * cp] = a1;
      *(f32x2*)&LX[o][2][2 * cp] = a2;
      *(f32x2*)&LX[o][3][2 * cp] = a3;
      wavebar<true>(&cXZbar, epX);  // partials visible
      if (t >= RDEPTH) {
        while (__hip_atomic_load(&cCRITdone, __ATOMIC_RELAXED,
                                 __HIP_MEMORY_SCOPE_WORKGROUP) <
               4 * (t - RDEPTH + 1)) {
          __builtin_amdgcn_s_sleep(1);
        }
        asm volatile("" ::: "memory");
      }
      {
        const int b2 = idx >> 6, c3 = idx & 63;
        float ssum = 0.f;
#pragma unroll
        for (int oo = 0; oo < 8; ++oo) ssum += LX[oo][b2][c3];
        RING[t & (RDEPTH - 1)][b2][c3] = ssum;
      }
      wavebar<true>(&cXZbar, epX);  // reduce complete (guards LX overwrite)
      if (idx == 0) {
        asm volatile("s_waitcnt lgkmcnt(0)" ::: "memory");
        __hip_atomic_fetch_add(&cXZdone, 1, __ATOMIC_RELAXED,
                               __HIP_MEMORY_SCOPE_WORKGROUP);
      }
    }
  }
}

extern "C" void kernel_launch(void* const* d_in, const int* in_sizes, int n_in,
                              void* d_out, int out_size, void* d_ws, size_t ws_size,
                              hipStream_t stream) {
  const float* x    = (const float*)d_in[0];
  const float* Wk   = (const float*)d_in[1];
  const float* Wr   = (const float*)d_in[2];
  const float* bias = (const float*)d_in[3];
  float* out = (float*)d_out;

  // Sentinel-fill the h history (graph-capturable async memset).
  hipMemsetAsync(out, 0xFF, (size_t)out_size * sizeof(float), stream);
  lstm_persistent<<<256, 512, 0, stream>>>(x, Wk, Wr, bias, out);
}